// Round 1
// baseline (64.110 us; speedup 1.0000x reference)
//
#include <hip/hip_runtime.h>
#include <hip/hip_bf16.h>
#include <hip/hip_fp16.h>

#define NN 1024   // nodes
#define FD 64     // feature dim (in == out)
#define BB 32     // batch

typedef __attribute__((ext_vector_type(4))) float    f32x4;
typedef __attribute__((ext_vector_type(8))) _Float16 f16x8;

static __device__ __forceinline__ unsigned short f2hu(float x) {
  _Float16 h = (_Float16)x;
  return __builtin_bit_cast(unsigned short, h);
}
// order-preserving float<->uint encoding for atomicMax
static __device__ __forceinline__ unsigned fenc(float x) {
  unsigned u = __float_as_uint(x);
  return (u & 0x80000000u) ? ~u : (u | 0x80000000u);
}
static __device__ __forceinline__ float fdec(unsigned u) {
  u = (u & 0x80000000u) ? (u & 0x7FFFFFFFu) : ~u;
  return __uint_as_float(u);
}

// ---------------- Kernel 1: h = x@W (fp32), f = h@a1, g = h@a2, hT (fp16, o-major), batch maxes
__global__ __launch_bounds__(256) void gat_k1(
    const float* __restrict__ x, const float* __restrict__ W,
    const float* __restrict__ av, float* __restrict__ fv,
    float* __restrict__ gv, unsigned short* __restrict__ hT,
    unsigned* __restrict__ fgmax)
{
  __shared__ __align__(16) float Wl[FD * FD];        // 16 KB
  __shared__ __align__(16) float xl[FD * 68];        // padded rows (bank spread)
  __shared__ __align__(16) unsigned short tl[FD * FD]; // transposed h tile, fp16, swizzled
  __shared__ __align__(16) float al[2 * FD];

  const int tid = threadIdx.x;
  const int b   = blockIdx.x >> 4;
  const int n0  = (blockIdx.x & 15) << 6;

  if (tid < 32) ((f32x4*)al)[tid] = ((const f32x4*)av)[tid];
  {
    const int r  = tid >> 2;
    const int cb = (tid & 3) << 2;   // float4-chunk base (of 16 per row)
    const f32x4* Wg = (const f32x4*)W;
    const f32x4* xg = (const f32x4*)(x + ((size_t)(b * NN + n0)) * FD);
#pragma unroll
    for (int k = 0; k < 4; ++k) {
      f32x4 wv = Wg[r * 16 + cb + k];
      f32x4 xv = xg[r * 16 + cb + k];
      *(f32x4*)(Wl + r * FD + ((cb + k) << 2)) = wv;
      *(f32x4*)(xl + r * 68 + ((cb + k) << 2)) = xv;
    }
  }
  __syncthreads();

  const int r  = tid >> 2;          // row in tile
  const int o0 = (tid & 3) << 4;    // 16 output features
  float acc[16];
#pragma unroll
  for (int i = 0; i < 16; ++i) acc[i] = 0.f;

#pragma unroll 8
  for (int f = 0; f < FD; ++f) {
    float xv = xl[r * 68 + f];
    const f32x4* wr = (const f32x4*)(Wl + f * FD + o0);
#pragma unroll
    for (int c = 0; c < 4; ++c) {
      f32x4 wv = wr[c];
      acc[c * 4 + 0] += xv * wv.x;
      acc[c * 4 + 1] += xv * wv.y;
      acc[c * 4 + 2] += xv * wv.z;
      acc[c * 4 + 3] += xv * wv.w;
    }
  }

  float fp = 0.f, gp = 0.f;
#pragma unroll
  for (int i = 0; i < 16; ++i) {
    fp += acc[i] * al[o0 + i];
    gp += acc[i] * al[FD + o0 + i];
  }
  fp += __shfl_xor(fp, 1); fp += __shfl_xor(fp, 2);
  gp += __shfl_xor(gp, 1); gp += __shfl_xor(gp, 2);
  if ((tid & 3) == 0) {
    fv[b * NN + n0 + r] = fp;
    gv[b * NN + n0 + r] = gp;
  }
  // per-batch maxes (all lanes hold their row's f/g after the 4-lane reduce)
  float fw = fp, gw = gp;
#pragma unroll
  for (int m = 4; m < 64; m <<= 1) {
    fw = fmaxf(fw, __shfl_xor(fw, m));
    gw = fmaxf(gw, __shfl_xor(gw, m));
  }
  if ((tid & 63) == 0) {
    atomicMax(fgmax + 2 * b,     fenc(fw));
    atomicMax(fgmax + 2 * b + 1, fenc(gw));
  }

  // write h transposed into LDS (fp16, XOR-swizzled 16B chunks), then coalesced out
#pragma unroll
  for (int i = 0; i < 16; ++i) {
    int o  = o0 + i;
    int sw = (o ^ (o >> 3)) & 7;
    tl[o * FD + ((((r >> 3) ^ sw) << 3) | (r & 7))] = f2hu(acc[i]);
  }
  __syncthreads();
  {
    const int c2 = tid & 7;
#pragma unroll
    for (int hh = 0; hh < 2; ++hh) {
      int o  = (tid >> 3) + 32 * hh;
      int sw = (o ^ (o >> 3)) & 7;
      f32x4 v = *(const f32x4*)(tl + o * FD + ((c2 ^ sw) << 3));
      *(f32x4*)(hT + ((size_t)(b * FD + o)) * NN + n0 + c2 * 8) = v;
    }
  }
}

// ---------------- Kernel 2: fused masked-softmax attention + PV (MFMA f16) + elu
__global__ __launch_bounds__(256) void gat_k2(
    const int* __restrict__ adj, const float* __restrict__ fv,
    const float* __restrict__ gv, const unsigned short* __restrict__ hT,
    const unsigned* __restrict__ fgmax, float* __restrict__ out)
{
  __shared__ __align__(16) unsigned short Pl[FD * FD]; // P tile fp16, swizzled
  __shared__ __align__(16) unsigned short Hl[FD * FD]; // hT tile fp16, swizzled
  __shared__ float dLds[FD];

  const int tid  = threadIdx.x;
  const int b    = blockIdx.x >> 4;
  const int i0   = (blockIdx.x & 15) << 6;
  const int lane = tid & 63, w = tid >> 6;
  const int q = tid >> 4, s = tid & 15;   // p-compute mapping: rows q+16k, cols 4s..4s+3
  const int ro = tid >> 3, c = tid & 7;   // hT staging mapping
  const int bN = b * NN;

  const float sm = fdec(fgmax[2 * b]) + fdec(fgmax[2 * b + 1]);
  const float Cb = fmaxf(sm, 0.2f * sm);  // >= max masked score; p = exp(e-Cb) <= 1 (fp16-safe)

  const int*            adjS = adj + ((size_t)bN + i0 + q) * NN + s * 4;
  const float*          gvS  = gv + bN + s * 4;
  const unsigned short* hTS  = hT + ((size_t)b * FD + ro) * NN + c * 8;

  float fr[4];
#pragma unroll
  for (int k = 0; k < 4; ++k) fr[k] = fv[bN + i0 + q + 16 * k];

  float dAcc[4] = {0.f, 0.f, 0.f, 0.f};
  f32x4 acc[4];
#pragma unroll
  for (int n = 0; n < 4; ++n) acc[n] = (f32x4){0.f, 0.f, 0.f, 0.f};

  int4 A_a0, A_a1, A_a2, A_a3, A_h0, A_h1; f32x4 A_g;
  int4 B_a0, B_a1, B_a2, B_a3, B_h0, B_h1; f32x4 B_g;

#define TLOAD(P, jt) do {                                        \
    const int j0_ = (jt) << 6;                                   \
    P##a0 = *(const int4*)(adjS + j0_);                          \
    P##a1 = *(const int4*)(adjS + j0_ + 16 * NN);                \
    P##a2 = *(const int4*)(adjS + j0_ + 32 * NN);                \
    P##a3 = *(const int4*)(adjS + j0_ + 48 * NN);                \
    P##g  = *(const f32x4*)(gvS + j0_);                          \
    P##h0 = *(const int4*)(hTS + j0_);                           \
    P##h1 = *(const int4*)(hTS + (size_t)32 * NN + j0_);         \
  } while (0)

#define PROW(avv, gg, k) do {                                            \
    const int row_ = q + 16 * (k);                                       \
    float e0 = fr[k] + gg.x; e0 = fmaxf(e0, 0.2f * e0) - Cb;             \
    float e1 = fr[k] + gg.y; e1 = fmaxf(e1, 0.2f * e1) - Cb;             \
    float e2 = fr[k] + gg.z; e2 = fmaxf(e2, 0.2f * e2) - Cb;             \
    float e3 = fr[k] + gg.w; e3 = fmaxf(e3, 0.2f * e3) - Cb;             \
    float p0 = (avv.x > 0) ? __expf(e0) : 0.f;                           \
    float p1 = (avv.y > 0) ? __expf(e1) : 0.f;                           \
    float p2 = (avv.z > 0) ? __expf(e2) : 0.f;                           \
    float p3 = (avv.w > 0) ? __expf(e3) : 0.f;                           \
    dAcc[k] += (p0 + p1) + (p2 + p3);                                    \
    uint2 uv_;                                                           \
    uv_.x = (unsigned)f2hu(p0) | ((unsigned)f2hu(p1) << 16);             \
    uv_.y = (unsigned)f2hu(p2) | ((unsigned)f2hu(p3) << 16);             \
    *(uint2*)(Pl + row_ * FD +                                           \
              ((((s >> 1) ^ (row_ & 7)) << 3) | ((s & 1) << 2))) = uv_;  \
  } while (0)

#define TPROC(P) do {                                                    \
    PROW(P##a0, P##g, 0); PROW(P##a1, P##g, 1);                          \
    PROW(P##a2, P##g, 2); PROW(P##a3, P##g, 3);                          \
    *(int4*)(Hl + ro * FD + ((c ^ (ro & 7)) << 3)) = P##h0;              \
    *(int4*)(Hl + (ro + 32) * FD + ((c ^ ((ro + 32) & 7)) << 3)) = P##h1;\
  } while (0)

#define MSTEP() do {                                                       \
    const int m16_ = lane & 15, hi_ = lane >> 4;                           \
    const int ar_ = w * 16 + m16_;                                         \
    const f16x8 a0_ = *(const f16x8*)(Pl + ar_ * FD + (((hi_)     ^ (ar_ & 7)) << 3)); \
    const f16x8 a1_ = *(const f16x8*)(Pl + ar_ * FD + (((hi_ + 4) ^ (ar_ & 7)) << 3)); \
    _Pragma("unroll")                                                      \
    for (int n_ = 0; n_ < 4; ++n_) {                                       \
      const int o_ = n_ * 16 + m16_;                                       \
      const f16x8 b0_ = *(const f16x8*)(Hl + o_ * FD + (((hi_)     ^ (o_ & 7)) << 3)); \
      const f16x8 b1_ = *(const f16x8*)(Hl + o_ * FD + (((hi_ + 4) ^ (o_ & 7)) << 3)); \
      acc[n_] = __builtin_amdgcn_mfma_f32_16x16x32_f16(a0_, b0_, acc[n_], 0, 0, 0);    \
      acc[n_] = __builtin_amdgcn_mfma_f32_16x16x32_f16(a1_, b1_, acc[n_], 0, 0, 0);    \
    }                                                                      \
  } while (0)

  TLOAD(A_, 0);
  for (int tt = 0; tt < 8; ++tt) {
    TLOAD(B_, 2 * tt + 1);          // prefetch next tile while processing current
    TPROC(A_);
    __syncthreads();
    MSTEP();
    __syncthreads();
    TLOAD(A_, (tt < 7) ? (2 * tt + 2) : 15);
    TPROC(B_);
    __syncthreads();
    MSTEP();
    __syncthreads();
  }

  // denominator: reduce per-thread partials across the 16 lanes covering each row
#pragma unroll
  for (int m = 1; m < 16; m <<= 1) {
    dAcc[0] += __shfl_xor(dAcc[0], m);
    dAcc[1] += __shfl_xor(dAcc[1], m);
    dAcc[2] += __shfl_xor(dAcc[2], m);
    dAcc[3] += __shfl_xor(dAcc[3], m);
  }
  if (s == 0) {
    dLds[q] = dAcc[0]; dLds[q + 16] = dAcc[1];
    dLds[q + 32] = dAcc[2]; dLds[q + 48] = dAcc[3];
  }
  __syncthreads();

  const int m16 = lane & 15, hi4 = lane >> 4;
  float* outp = out + ((size_t)(bN + i0 + w * 16 + hi4 * 4)) * FD + m16;
#pragma unroll
  for (int rr = 0; rr < 4; ++rr) {
    float d   = dLds[w * 16 + hi4 * 4 + rr];
    float inv = d > 0.f ? 1.f / d : 0.f;
#pragma unroll
    for (int n = 0; n < 4; ++n) {
      float v = acc[n][rr] * inv;
      v = v > 0.f ? v : (__expf(v) - 1.f);   // elu (alpha=1)
      outp[(size_t)rr * FD + n * 16] = v;
    }
  }
#undef TLOAD
#undef PROW
#undef TPROC
#undef MSTEP
}

extern "C" void kernel_launch(void* const* d_in, const int* in_sizes, int n_in,
                              void* d_out, int out_size, void* d_ws, size_t ws_size,
                              hipStream_t stream) {
  const float* x   = (const float*)d_in[0];
  const int*   adj = (const int*)d_in[1];
  const float* W   = (const float*)d_in[2];
  const float* a   = (const float*)d_in[3];
  float* out = (float*)d_out;

  // workspace: hT fp16 [B][FD][NN] (4 MB) | f [B][NN] | g [B][NN] | fgmax[2B]
  unsigned short* hT = (unsigned short*)d_ws;
  float* fv = (float*)((char*)d_ws + (size_t)BB * FD * NN * 2);
  float* gv = fv + (size_t)BB * NN;
  unsigned* fgmax = (unsigned*)(gv + (size_t)BB * NN);

  hipMemsetAsync(fgmax, 0, 2 * BB * sizeof(unsigned), stream);
  gat_k1<<<dim3(BB * 16), dim3(256), 0, stream>>>(x, W, a, fv, gv, hT, fgmax);
  gat_k2<<<dim3(BB * 16), dim3(256), 0, stream>>>(adj, fv, gv, hT, fgmax, out);
}

// Round 2
// 42.206 us; speedup vs baseline: 1.5190x; 1.5190x over previous
//
#include <hip/hip_runtime.h>
#include <hip/hip_bf16.h>
#include <hip/hip_fp16.h>

#define NN 1024   // nodes
#define FD 64     // feature dim (in == out)
#define BB 32     // batch

typedef __attribute__((ext_vector_type(4))) float    f32x4;
typedef __attribute__((ext_vector_type(8))) _Float16 f16x8;

static __device__ __forceinline__ unsigned short f2hu(float x) {
  _Float16 h = (_Float16)x;
  return __builtin_bit_cast(unsigned short, h);
}

// ---------------- Kernel 1: h = x@W (fp32), f = h@a1, g = h@a2, hT (fp16, o-major)
__global__ __launch_bounds__(256) void gat_k1(
    const float* __restrict__ x, const float* __restrict__ W,
    const float* __restrict__ av, float* __restrict__ fv,
    float* __restrict__ gv, unsigned short* __restrict__ hT)
{
  __shared__ __align__(16) float Wl[FD * FD];        // 16 KB
  __shared__ __align__(16) float xl[FD * 68];        // padded rows (bank spread)
  __shared__ __align__(16) unsigned short tl[FD * FD]; // transposed h tile, fp16, swizzled
  __shared__ __align__(16) float al[2 * FD];

  const int tid = threadIdx.x;
  const int b   = blockIdx.x >> 4;
  const int n0  = (blockIdx.x & 15) << 6;

  if (tid < 32) ((f32x4*)al)[tid] = ((const f32x4*)av)[tid];
  {
    const int r  = tid >> 2;
    const int cb = (tid & 3) << 2;   // float4-chunk base (of 16 per row)
    const f32x4* Wg = (const f32x4*)W;
    const f32x4* xg = (const f32x4*)(x + ((size_t)(b * NN + n0)) * FD);
#pragma unroll
    for (int k = 0; k < 4; ++k) {
      f32x4 wv = Wg[r * 16 + cb + k];
      f32x4 xv = xg[r * 16 + cb + k];
      *(f32x4*)(Wl + r * FD + ((cb + k) << 2)) = wv;
      *(f32x4*)(xl + r * 68 + ((cb + k) << 2)) = xv;
    }
  }
  __syncthreads();

  const int r  = tid >> 2;          // row in tile
  const int o0 = (tid & 3) << 4;    // 16 output features
  float acc[16];
#pragma unroll
  for (int i = 0; i < 16; ++i) acc[i] = 0.f;

#pragma unroll 8
  for (int f = 0; f < FD; ++f) {
    float xv = xl[r * 68 + f];
    const f32x4* wr = (const f32x4*)(Wl + f * FD + o0);
#pragma unroll
    for (int c = 0; c < 4; ++c) {
      f32x4 wv = wr[c];
      acc[c * 4 + 0] += xv * wv.x;
      acc[c * 4 + 1] += xv * wv.y;
      acc[c * 4 + 2] += xv * wv.z;
      acc[c * 4 + 3] += xv * wv.w;
    }
  }

  float fp = 0.f, gp = 0.f;
#pragma unroll
  for (int i = 0; i < 16; ++i) {
    fp += acc[i] * al[o0 + i];
    gp += acc[i] * al[FD + o0 + i];
  }
  fp += __shfl_xor(fp, 1); fp += __shfl_xor(fp, 2);
  gp += __shfl_xor(gp, 1); gp += __shfl_xor(gp, 2);
  if ((tid & 3) == 0) {
    fv[b * NN + n0 + r] = fp;
    gv[b * NN + n0 + r] = gp;
  }

  // write h transposed into LDS (fp16, XOR-swizzled 16B chunks), then coalesced out
#pragma unroll
  for (int i = 0; i < 16; ++i) {
    int o  = o0 + i;
    int sw = (o ^ (o >> 3)) & 7;
    tl[o * FD + ((((r >> 3) ^ sw) << 3) | (r & 7))] = f2hu(acc[i]);
  }
  __syncthreads();
  {
    const int c2 = tid & 7;
#pragma unroll
    for (int hh = 0; hh < 2; ++hh) {
      int o  = (tid >> 3) + 32 * hh;
      int sw = (o ^ (o >> 3)) & 7;
      f32x4 v = *(const f32x4*)(tl + o * FD + ((c2 ^ sw) << 3));
      *(f32x4*)(hT + ((size_t)(b * FD + o)) * NN + n0 + c2 * 8) = v;
    }
  }
}

// ---------------- Kernel 2: fused masked-softmax attention + PV (MFMA f16) + elu
// 32-row i-tiles -> 1024 blocks (4/CU) for latency hiding. g staged in LDS.
__global__ __launch_bounds__(256) void gat_k2(
    const int* __restrict__ adj, const float* __restrict__ fv,
    const float* __restrict__ gv, const unsigned short* __restrict__ hT,
    float* __restrict__ out)
{
  __shared__ __align__(16) unsigned short Pl[32 * FD]; // P tile fp16, swizzled (4 KB)
  __shared__ __align__(16) unsigned short Hl[FD * FD]; // hT tile fp16, swizzled (8 KB)
  __shared__ __align__(16) float gl[NN];               // g row for this batch (4 KB)
  __shared__ float dLds[32];
  __shared__ float red[8];

  const int tid  = threadIdx.x;
  const int b    = blockIdx.x >> 5;
  const int i0   = (blockIdx.x & 31) << 5;
  const int lane = tid & 63, w = tid >> 6;
  const int q = tid >> 3, s = tid & 7;   // row q (0..31), col-chunk s (0..7)
  const int bN = b * NN;

  // ---- prologue: stage g into LDS, per-block shift Cb = lrelu(max f_block + max g)
  f32x4 g4 = *(const f32x4*)(gv + bN + tid * 4);
  *(f32x4*)(gl + tid * 4) = g4;
  float gm = fmaxf(fmaxf(g4.x, g4.y), fmaxf(g4.z, g4.w));
  float fm = fv[bN + i0 + (tid & 31)];
#pragma unroll
  for (int m = 1; m < 64; m <<= 1) {
    gm = fmaxf(gm, __shfl_xor(gm, m));
    fm = fmaxf(fm, __shfl_xor(fm, m));
  }
  if (lane == 0) { red[w * 2] = gm; red[w * 2 + 1] = fm; }
  const float fr = fv[bN + i0 + q];
  __syncthreads();
  gm = fmaxf(fmaxf(red[0], red[2]), fmaxf(red[4], red[6]));
  fm = fmaxf(fmaxf(red[1], red[3]), fmaxf(red[5], red[7]));
  const float sm = fm + gm;
  const float Cb = fmaxf(sm, 0.2f * sm);  // >= max masked score; p = exp(e-Cb) <= 1

  const int*            adjS = adj + ((size_t)(bN + i0 + q)) * NN + s * 4;
  const unsigned short* hTS  = hT + ((size_t)(b * FD + q)) * NN + s * 8;

  float dAcc = 0.f;
  f32x4 acc[2];
  acc[0] = (f32x4){0.f, 0.f, 0.f, 0.f};
  acc[1] = (f32x4){0.f, 0.f, 0.f, 0.f};

  int4 A_a0, A_a1, A_h0, A_h1;
  int4 B_a0, B_a1, B_h0, B_h1;

#define TLOAD(P, jt) do {                                \
    const int j0_ = (jt) << 6;                           \
    P##a0 = *(const int4*)(adjS + j0_);                  \
    P##a1 = *(const int4*)(adjS + j0_ + 32);             \
    P##h0 = *(const int4*)(hTS + j0_);                   \
    P##h1 = *(const int4*)(hTS + (size_t)32 * NN + j0_); \
  } while (0)

#define PQUAD(avv, gg, half) do {                                          \
    float e0 = fr + gg.x; e0 = fmaxf(e0, 0.2f * e0) - Cb;                  \
    float e1 = fr + gg.y; e1 = fmaxf(e1, 0.2f * e1) - Cb;                  \
    float e2 = fr + gg.z; e2 = fmaxf(e2, 0.2f * e2) - Cb;                  \
    float e3 = fr + gg.w; e3 = fmaxf(e3, 0.2f * e3) - Cb;                  \
    float p0 = (avv.x > 0) ? __expf(e0) : 0.f;                             \
    float p1 = (avv.y > 0) ? __expf(e1) : 0.f;                             \
    float p2 = (avv.z > 0) ? __expf(e2) : 0.f;                             \
    float p3 = (avv.w > 0) ? __expf(e3) : 0.f;                             \
    dAcc += (p0 + p1) + (p2 + p3);                                         \
    uint2 uv_;                                                             \
    uv_.x = (unsigned)f2hu(p0) | ((unsigned)f2hu(p1) << 16);               \
    uv_.y = (unsigned)f2hu(p2) | ((unsigned)f2hu(p3) << 16);               \
    *(uint2*)(Pl + q * FD +                                                \
        (((((half) << 2) + (s >> 1)) ^ (q & 7)) << 3) + ((s & 1) << 2)) = uv_; \
  } while (0)

#define TPROC(P, jt) do {                                                  \
    const int jg_ = (jt) << 6;                                             \
    f32x4 g0_ = *(const f32x4*)(gl + jg_ + s * 4);                         \
    f32x4 g1_ = *(const f32x4*)(gl + jg_ + 32 + s * 4);                    \
    PQUAD(P##a0, g0_, 0); PQUAD(P##a1, g1_, 1);                            \
    *(int4*)(Hl + q * FD + ((s ^ (q & 7)) << 3)) = P##h0;                  \
    *(int4*)(Hl + (q + 32) * FD + ((s ^ (q & 7)) << 3)) = P##h1;           \
  } while (0)

#define MSTEP() do {                                                       \
    const int m16_ = lane & 15, hi_ = lane >> 4;                           \
    const int ar_ = ((w & 1) << 4) + m16_;                                 \
    const f16x8 a0_ = *(const f16x8*)(Pl + ar_ * FD + (((hi_)     ^ (ar_ & 7)) << 3)); \
    const f16x8 a1_ = *(const f16x8*)(Pl + ar_ * FD + (((hi_ + 4) ^ (ar_ & 7)) << 3)); \
    _Pragma("unroll")                                                      \
    for (int n_ = 0; n_ < 2; ++n_) {                                       \
      const int o_ = ((w >> 1) << 5) + (n_ << 4) + m16_;                   \
      const f16x8 b0_ = *(const f16x8*)(Hl + o_ * FD + (((hi_)     ^ (o_ & 7)) << 3)); \
      const f16x8 b1_ = *(const f16x8*)(Hl + o_ * FD + (((hi_ + 4) ^ (o_ & 7)) << 3)); \
      acc[n_] = __builtin_amdgcn_mfma_f32_16x16x32_f16(a0_, b0_, acc[n_], 0, 0, 0);    \
      acc[n_] = __builtin_amdgcn_mfma_f32_16x16x32_f16(a1_, b1_, acc[n_], 0, 0, 0);    \
    }                                                                      \
  } while (0)

  TLOAD(A_, 0);
  for (int tt = 0; tt < 8; ++tt) {
    TLOAD(B_, 2 * tt + 1);          // prefetch next tile while processing current
    TPROC(A_, 2 * tt);
    __syncthreads();
    MSTEP();
    __syncthreads();
    TLOAD(A_, (tt < 7) ? (2 * tt + 2) : 15);
    TPROC(B_, 2 * tt + 1);
    __syncthreads();
    MSTEP();
    __syncthreads();
  }

  // denominator: 8 threads (s=0..7) share row q
  dAcc += __shfl_xor(dAcc, 1);
  dAcc += __shfl_xor(dAcc, 2);
  dAcc += __shfl_xor(dAcc, 4);
  if (s == 0) dLds[q] = dAcc;
  __syncthreads();

  const int m16 = lane & 15, hi4 = lane >> 4;
  const int wr = (w & 1) << 4, wc = (w >> 1) << 5;
  float* outp = out + ((size_t)(bN + i0 + wr + hi4 * 4)) * FD + wc + m16;
#pragma unroll
  for (int rr = 0; rr < 4; ++rr) {
    float d   = dLds[wr + hi4 * 4 + rr];
    float inv = d > 0.f ? 1.f / d : 0.f;
#pragma unroll
    for (int n = 0; n < 2; ++n) {
      float v = acc[n][rr] * inv;
      v = v > 0.f ? v : (__expf(v) - 1.f);   // elu (alpha=1)
      outp[(size_t)rr * FD + n * 16] = v;
    }
  }
#undef TLOAD
#undef PQUAD
#undef TPROC
#undef MSTEP
}

extern "C" void kernel_launch(void* const* d_in, const int* in_sizes, int n_in,
                              void* d_out, int out_size, void* d_ws, size_t ws_size,
                              hipStream_t stream) {
  const float* x   = (const float*)d_in[0];
  const int*   adj = (const int*)d_in[1];
  const float* W   = (const float*)d_in[2];
  const float* a   = (const float*)d_in[3];
  float* out = (float*)d_out;

  // workspace: hT fp16 [B][FD][NN] (4 MB) | f [B][NN] | g [B][NN]
  unsigned short* hT = (unsigned short*)d_ws;
  float* fv = (float*)((char*)d_ws + (size_t)BB * FD * NN * 2);
  float* gv = fv + (size_t)BB * NN;

  gat_k1<<<dim3(BB * 16), dim3(256), 0, stream>>>(x, W, a, fv, gv, hT);
  gat_k2<<<dim3(BB * 32), dim3(256), 0, stream>>>(adj, fv, gv, hT, out);
}